// Round 12
// baseline (62.132 us; speedup 1.0000x reference)
//
#include <hip/hip_runtime.h>
#include <math.h>

#define N_PTS   4000000
#define NQUADS  (N_PTS / 4)        // 1,000,000 quads; 1 quad = 4 pts = 12 floats
#define NTHREADS 256
#define NF4      (3 * NQUADS)      // 3,000,000 float4s in the stream
#define NTILES   ((NQUADS + NTHREADS - 1) / NTHREADS)   // 3907 tiles of 256 quads
#define NBLOCKS_P ((NTILES + 1) / 2)                    // 1954 blocks, 2 tiles each

// ---------------------------------------------------------------------------
// Round 12 = round 11 structure (LDS-transpose + register prefetch, verified
// -2.6us) with two contained deltas:
//  (1) loss fused into proj via device-scope ATOMICS (no threadfence - round-3
//      lesson). Block partial -> atomicAdd(sum); counter modulo-N detects the
//      last block regardless of initial poison; last block atomicExch(sum,0)
//      fetches the total AND re-zeroes for the next graph replay (no memset).
//      Ordering: float-add result consumed (asm) before counter-add, so
//      counter==last implies all float-adds complete.
//  (2) redundant barrier removed: coalesced store reads LDS slots
//      {t,t+256,t+512} and the stage writes the SAME slots from the SAME
//      thread - in-thread DS ordering suffices.
// ---------------------------------------------------------------------------
__global__ __launch_bounds__(NTHREADS) void proj_kernel(
    const float4* __restrict__ pts,
    const float* __restrict__ xp, const float* __restrict__ yp,
    const float* __restrict__ zp, const float* __restrict__ rollp,
    const float* __restrict__ pitchp, const float* __restrict__ yawp,
    float4* __restrict__ vout,
    float* __restrict__ sum_slot, unsigned int* __restrict__ counter,
    float* __restrict__ loss_out)
{
    __shared__ float sRT[12];
    __shared__ float4 tile[3 * NTHREADS];      // 12 KiB
    __shared__ float sred[NTHREADS / 64];

    const int t = threadIdx.x;
    const int tbase = blockIdx.x * 2;

    // --- prologue: issue tile0 loads, overlap thread-0 trig with latency ---
    float4 p0 = make_float4(0.f, 0.f, 0.f, 0.f), p1 = p0, p2 = p0;
    {
        const size_t fb = (size_t)tbase * (3 * NTHREADS) + t;
        if (fb                < NF4) p0 = pts[fb];
        if (fb +     NTHREADS < NF4) p1 = pts[fb + NTHREADS];
        if (fb + 2 * NTHREADS < NF4) p2 = pts[fb + 2 * NTHREADS];
    }
    if (t == 0) {
        const float r = rollp[0], p = pitchp[0], ya = yawp[0];
        const float cr = cosf(r),  sr = sinf(r);
        const float cp = cosf(p),  sp = sinf(p);
        const float cy = cosf(ya), sy = sinf(ya);
        // R = Rx @ Ry @ Rz, row-major
        sRT[0] = cp * cy;                 sRT[1] = -cp * sy;                sRT[2] = sp;
        sRT[3] = cr * sy + sr * sp * cy;  sRT[4] = cr * cy - sr * sp * sy;  sRT[5] = -sr * cp;
        sRT[6] = sr * sy - cr * sp * cy;  sRT[7] = sr * cy + cr * sp * sy;  sRT[8] = cr * cp;
        sRT[9] = xp[0]; sRT[10] = yp[0]; sRT[11] = zp[0];
    }
    tile[t]                = p0;
    tile[t + NTHREADS]     = p1;
    tile[t + 2 * NTHREADS] = p2;
    __syncthreads();                                    // tile0 + sRT visible

    const float R00 = sRT[0], R01 = sRT[1], R02 = sRT[2];
    const float R10 = sRT[3], R11 = sRT[4], R12 = sRT[5];
    const float R20 = sRT[6], R21 = sRT[7], R22 = sRT[8];
    const float Tx  = sRT[9], Ty  = sRT[10], Tz = sRT[11];

    float acc = 0.0f;

#pragma unroll
    for (int i = 0; i < 2; ++i) {
        const int tid = tbase + i;

        // Read own quad (3x ds_read_b128 from own 48B region).
        const float4* __restrict__ mt = (const float4*)((const float*)tile + 12 * t);
        const float4 a = mt[0];
        const float4 b = mt[1];
        const float4 c = mt[2];

        // Prefetch next tile -> regs; latency hides under compute + store.
        if (i == 0) {
            const size_t fb = (size_t)(tbase + 1) * (3 * NTHREADS) + t;
            p0 = make_float4(0.f, 0.f, 0.f, 0.f); p1 = p0; p2 = p0;
            if (fb                < NF4) p0 = pts[fb];
            if (fb +     NTHREADS < NF4) p1 = pts[fb + NTHREADS];
            if (fb + 2 * NTHREADS < NF4) p2 = pts[fb + 2 * NTHREADS];
        }

        const int q = tid * NTHREADS + t;               // global quad index
        float4 o0 = make_float4(0.f, 0.f, 0.f, 0.f), o1 = o0, o2 = o0;
        if (q < NQUADS) {
            const float px[4] = {a.x, a.w, b.z, c.y};
            const float py[4] = {a.y, b.x, b.w, c.z};
            const float pz[4] = {a.z, b.y, c.x, c.w};
            float vx[4], vy[4], vz[4];

#pragma unroll
            for (int k = 0; k < 4; ++k) {
                const float q0 = px[k] - Tx;
                const float q1 = py[k] - Ty;
                const float q2 = pz[k] - Tz;
                // v = q @ R   (v_j = sum_i q_i * R[i][j])
                const float v0 = q0 * R00 + q1 * R10 + q2 * R20;
                const float v1 = q0 * R01 + q1 * R11 + q2 * R21;
                const float v2 = q0 * R02 + q1 * R12 + q2 * R22;

                const bool dist = (v2 > 1.0f) && (v2 < 10.0f);

                // ph = v @ K^T ; ph[2] == v2
                const float ph0 = v0 * 600.0f + v2 * 640.0f;
                const float ph1 = v1 * 600.0f + v2 * 360.0f;
                const float u = ph0 / v2;        // IEEE div: mask bit-exactness
                const float w = ph1 / v2;
                const bool fov = (v2 > 0.0f) && (u > 1.0f) && (u < 1279.0f) &&
                                 (w > 1.0f) && (w < 719.0f);
                const bool m = dist && fov;

                const float d  = sqrtf(v0 * v0 + v1 * v1 + v2 * v2);
                const float t2 = (d - 4.0f) * 0.5f;     // (d - MU) / SIGMA
                acc += m ? __expf(-0.5f * t2 * t2) : 0.0f;

                vx[k] = m ? v0 : 0.0f;
                vy[k] = m ? v1 : 0.0f;
                vz[k] = m ? v2 : 0.0f;
            }
            o0 = make_float4(vx[0], vy[0], vz[0], vx[1]);
            o1 = make_float4(vy[1], vz[1], vx[2], vy[2]);
            o2 = make_float4(vz[2], vx[3], vy[3], vz[3]);
        }

        // Results to own region (only this thread touches it).
        float4* __restrict__ mtw = (float4*)((float*)tile + 12 * t);
        mtw[0] = o0; mtw[1] = o1; mtw[2] = o2;
        __syncthreads();                                // own-writes visible

        // Coalesced store (lane stride 16B), then stage next tile into the
        // SAME slots this thread just read - no barrier needed in between
        // (in-thread DS ordering).
        {
            const size_t fb = (size_t)tid * (3 * NTHREADS) + t;
            if (fb                < NF4) vout[fb]                = tile[t];
            if (fb +     NTHREADS < NF4) vout[fb + NTHREADS]     = tile[t + NTHREADS];
            if (fb + 2 * NTHREADS < NF4) vout[fb + 2 * NTHREADS] = tile[t + 2 * NTHREADS];
        }

        if (i == 0) {
            tile[t]                = p0;                // stage tile1
            tile[t + NTHREADS]     = p1;
            tile[t + 2 * NTHREADS] = p2;
            __syncthreads();                            // tile1 visible
        }
    }

    // Per-block deterministic reduction (acc=0 for invalid threads).
#pragma unroll
    for (int off = 32; off > 0; off >>= 1)
        acc += __shfl_down(acc, off, 64);
    if ((t & 63) == 0) sred[t >> 6] = acc;
    __syncthreads();
    if (t == 0) {
        float tot = 0.0f;
#pragma unroll
        for (int i = 0; i < NTHREADS / 64; ++i) tot += sred[i];

        // Device-scope atomic fusion (no fences). Float-add first; consume
        // its result so the counter-add provably issues after completion.
        const float r0 = atomicAdd(sum_slot, tot);
        asm volatile("" :: "v"(r0));
        const unsigned int old = atomicAdd(counter, 1u);
        if ((old % NBLOCKS_P) == NBLOCKS_P - 1) {
            // All blocks' float-adds complete. Fetch total and re-zero the
            // slot for the next replay in one atomic.
            const float total = atomicExch(sum_slot, 0.0f);
            loss_out[0] = 1.0f / (total + 1e-6f);
        }
    }
}

extern "C" void kernel_launch(void* const* d_in, const int* in_sizes, int n_in,
                              void* d_out, int out_size, void* d_ws, size_t ws_size,
                              hipStream_t stream) {
    const float4* pts  = (const float4*)d_in[0];
    const float* x     = (const float*)d_in[1];
    const float* y     = (const float*)d_in[2];
    const float* z     = (const float*)d_in[3];
    const float* roll  = (const float*)d_in[4];
    const float* pitch = (const float*)d_in[5];
    const float* yaw   = (const float*)d_in[6];

    float* out            = (float*)d_out;                  // [0..12M) verts, [12M] loss
    unsigned int* counter = (unsigned int*)d_ws;            // persists; modulo-N
    float* sum_slot       = (float*)d_ws + 1;               // self-zeroing chain

    proj_kernel<<<NBLOCKS_P, NTHREADS, 0, stream>>>(
        pts, x, y, z, roll, pitch, yaw,
        (float4*)out, sum_slot, counter, out + (size_t)3 * N_PTS);
}

// Round 13
// 24.704 us; speedup vs baseline: 2.5151x; 2.5151x over previous
//
#include <hip/hip_runtime.h>
#include <math.h>

#define N_PTS   4000000
#define NQUADS  (N_PTS / 4)        // 1,000,000 quads; 1 quad = 4 pts = 12 floats
#define NTHREADS 256
#define NF4      (3 * NQUADS)      // 3,000,000 float4s in the stream
#define NTILES   ((NQUADS + NTHREADS - 1) / NTHREADS)   // 3907 tiles of 256 quads
#define TPB      2                                      // tiles per block
#define NBLOCKS_P ((NTILES + TPB - 1) / TPB)            // 1954

// ---------------------------------------------------------------------------
// Round 13 = round 11 (verified 26.3us) + double-buffered LDS -> ONE barrier
// per tile, store moved to AFTER the barrier so its vmcnt drain hides under
// the next tile's compute instead of being drained by an immediate barrier.
// Loss back to a separate dispatch: round-12 lesson - float atomicAdd on one
// address compiles to a CAS loop on gfx950 (contention storm, +36us). No
// device fences (round-3 lesson). Plain stores (round-6 lesson).
// Per-slot hazard analysis: store reads buf[cur] slots {t,t+256,t+512};
// the next stage writes those same slots of buf[cur] from the SAME thread
// (in-thread DS order suffices); all cross-thread pairs are separated by
// the one barrier per iteration.
// ---------------------------------------------------------------------------
__global__ __launch_bounds__(NTHREADS) void proj_kernel(
    const float4* __restrict__ pts,
    const float* __restrict__ xp, const float* __restrict__ yp,
    const float* __restrict__ zp, const float* __restrict__ rollp,
    const float* __restrict__ pitchp, const float* __restrict__ yawp,
    float4* __restrict__ vout, float* __restrict__ partials)
{
    __shared__ float sRT[12];
    __shared__ float4 buf[2][3 * NTHREADS];    // 24 KiB double buffer
    __shared__ float sred[NTHREADS / 64];

    const int t = threadIdx.x;
    const int tbase = blockIdx.x * TPB;

    // --- prologue: issue tile0 loads; thread-0 trig overlaps load latency ---
    {
        float4 p0 = make_float4(0.f, 0.f, 0.f, 0.f), p1 = p0, p2 = p0;
        const size_t fb = (size_t)tbase * (3 * NTHREADS) + t;
        if (fb                < NF4) p0 = pts[fb];
        if (fb +     NTHREADS < NF4) p1 = pts[fb + NTHREADS];
        if (fb + 2 * NTHREADS < NF4) p2 = pts[fb + 2 * NTHREADS];

        if (t == 0) {
            const float r = rollp[0], p = pitchp[0], ya = yawp[0];
            const float cr = cosf(r),  sr = sinf(r);
            const float cp = cosf(p),  sp = sinf(p);
            const float cy = cosf(ya), sy = sinf(ya);
            // R = Rx @ Ry @ Rz, row-major
            sRT[0] = cp * cy;                 sRT[1] = -cp * sy;                sRT[2] = sp;
            sRT[3] = cr * sy + sr * sp * cy;  sRT[4] = cr * cy - sr * sp * sy;  sRT[5] = -sr * cp;
            sRT[6] = sr * sy - cr * sp * cy;  sRT[7] = sr * cy + cr * sp * sy;  sRT[8] = cr * cp;
            sRT[9] = xp[0]; sRT[10] = yp[0]; sRT[11] = zp[0];
        }
        buf[0][t]                = p0;
        buf[0][t + NTHREADS]     = p1;
        buf[0][t + 2 * NTHREADS] = p2;
    }
    __syncthreads();                                    // tile0 + sRT visible

    const float R00 = sRT[0], R01 = sRT[1], R02 = sRT[2];
    const float R10 = sRT[3], R11 = sRT[4], R12 = sRT[5];
    const float R20 = sRT[6], R21 = sRT[7], R22 = sRT[8];
    const float Tx  = sRT[9], Ty  = sRT[10], Tz = sRT[11];

    float acc = 0.0f;

#pragma unroll
    for (int i = 0; i < TPB; ++i) {
        const int tid = tbase + i;
        const int cur = i & 1;

        // Read own quad (3x ds_read_b128 from own 48B region of buf[cur]).
        const float4* __restrict__ mt =
            (const float4*)((const float*)&buf[cur][0] + 12 * t);
        const float4 a = mt[0];
        const float4 b = mt[1];
        const float4 c = mt[2];

        // Issue next tile's global loads; latency hides under compute.
        float4 q0 = make_float4(0.f, 0.f, 0.f, 0.f), q1 = q0, q2 = q0;
        if (i + 1 < TPB) {
            const size_t fb = (size_t)(tid + 1) * (3 * NTHREADS) + t;
            if (fb                < NF4) q0 = pts[fb];
            if (fb +     NTHREADS < NF4) q1 = pts[fb + NTHREADS];
            if (fb + 2 * NTHREADS < NF4) q2 = pts[fb + 2 * NTHREADS];
        }

        const int q = tid * NTHREADS + t;               // global quad index
        float4 o0 = make_float4(0.f, 0.f, 0.f, 0.f), o1 = o0, o2 = o0;
        if (q < NQUADS) {
            const float px[4] = {a.x, a.w, b.z, c.y};
            const float py[4] = {a.y, b.x, b.w, c.z};
            const float pz[4] = {a.z, b.y, c.x, c.w};
            float vx[4], vy[4], vz[4];

#pragma unroll
            for (int k = 0; k < 4; ++k) {
                const float q0f = px[k] - Tx;
                const float q1f = py[k] - Ty;
                const float q2f = pz[k] - Tz;
                // v = q @ R   (v_j = sum_i q_i * R[i][j])
                const float v0 = q0f * R00 + q1f * R10 + q2f * R20;
                const float v1 = q0f * R01 + q1f * R11 + q2f * R21;
                const float v2 = q0f * R02 + q1f * R12 + q2f * R22;

                const bool dist = (v2 > 1.0f) && (v2 < 10.0f);

                // ph = v @ K^T ; ph[2] == v2
                const float ph0 = v0 * 600.0f + v2 * 640.0f;
                const float ph1 = v1 * 600.0f + v2 * 360.0f;
                const float u = ph0 / v2;        // IEEE div: mask bit-exactness
                const float w = ph1 / v2;
                const bool fov = (v2 > 0.0f) && (u > 1.0f) && (u < 1279.0f) &&
                                 (w > 1.0f) && (w < 719.0f);
                const bool m = dist && fov;

                const float d  = sqrtf(v0 * v0 + v1 * v1 + v2 * v2);
                const float t2 = (d - 4.0f) * 0.5f;     // (d - MU) / SIGMA
                acc += m ? __expf(-0.5f * t2 * t2) : 0.0f;

                vx[k] = m ? v0 : 0.0f;
                vy[k] = m ? v1 : 0.0f;
                vz[k] = m ? v2 : 0.0f;
            }
            o0 = make_float4(vx[0], vy[0], vz[0], vx[1]);
            o1 = make_float4(vy[1], vz[1], vx[2], vy[2]);
            o2 = make_float4(vz[2], vx[3], vy[3], vz[3]);
        }

        // Writeback to own region of buf[cur].
        float4* __restrict__ mtw = (float4*)((float*)&buf[cur][0] + 12 * t);
        mtw[0] = o0; mtw[1] = o1; mtw[2] = o2;

        // Stage next tile into the OTHER buffer (waits on prefetch loads).
        if (i + 1 < TPB) {
            buf[cur ^ 1][t]                = q0;
            buf[cur ^ 1][t + NTHREADS]     = q1;
            buf[cur ^ 1][t + 2 * NTHREADS] = q2;
        }

        __syncthreads();    // the ONE barrier: writeback + stage visible

        // Coalesced store — LAST op of the iteration; its drain hides under
        // the next tile's readQuad/compute instead of an immediate barrier.
        {
            const size_t fb = (size_t)tid * (3 * NTHREADS) + t;
            if (fb                < NF4) vout[fb]                = buf[cur][t];
            if (fb +     NTHREADS < NF4) vout[fb + NTHREADS]     = buf[cur][t + NTHREADS];
            if (fb + 2 * NTHREADS < NF4) vout[fb + 2 * NTHREADS] = buf[cur][t + 2 * NTHREADS];
        }
    }

    // Per-block deterministic reduction (acc=0 for invalid threads).
#pragma unroll
    for (int off = 32; off > 0; off >>= 1)
        acc += __shfl_down(acc, off, 64);
    if ((t & 63) == 0) sred[t >> 6] = acc;
    __syncthreads();
    if (t == 0) {
        float tot = 0.0f;
#pragma unroll
        for (int i = 0; i < NTHREADS / 64; ++i) tot += sred[i];
        partials[blockIdx.x] = tot;
    }
}

// ---------------------------------------------------------------------------
// Loss kernel: sum partials in fixed order -> loss (cross-block sync point;
// no fences, no float atomics).
// ---------------------------------------------------------------------------
__global__ __launch_bounds__(256) void loss_kernel(const float* __restrict__ partials,
                                                   int n, float* __restrict__ loss_out) {
    __shared__ float sdata[4];
    float acc = 0.0f;
    for (int i = threadIdx.x; i < n; i += 256) acc += partials[i];
#pragma unroll
    for (int off = 32; off > 0; off >>= 1)
        acc += __shfl_down(acc, off, 64);
    if ((threadIdx.x & 63) == 0) sdata[threadIdx.x >> 6] = acc;
    __syncthreads();
    if (threadIdx.x == 0) {
        const float tot = sdata[0] + sdata[1] + sdata[2] + sdata[3];
        loss_out[0] = 1.0f / (tot + 1e-6f);
    }
}

extern "C" void kernel_launch(void* const* d_in, const int* in_sizes, int n_in,
                              void* d_out, int out_size, void* d_ws, size_t ws_size,
                              hipStream_t stream) {
    const float4* pts  = (const float4*)d_in[0];
    const float* x     = (const float*)d_in[1];
    const float* y     = (const float*)d_in[2];
    const float* z     = (const float*)d_in[3];
    const float* roll  = (const float*)d_in[4];
    const float* pitch = (const float*)d_in[5];
    const float* yaw   = (const float*)d_in[6];

    float* out   = (float*)d_out;   // [0..12M) verts, [12M] loss
    float* parts = (float*)d_ws;    // NBLOCKS_P floats

    proj_kernel<<<NBLOCKS_P, NTHREADS, 0, stream>>>(pts, x, y, z, roll, pitch, yaw,
                                                    (float4*)out, parts);
    loss_kernel<<<1, 256, 0, stream>>>(parts, NBLOCKS_P, out + (size_t)3 * N_PTS);
}

// Round 14
// 23.853 us; speedup vs baseline: 2.6048x; 1.0357x over previous
//
#include <hip/hip_runtime.h>
#include <math.h>

#define N_PTS   4000000
#define NQUADS  (N_PTS / 4)        // 1,000,000 quads; 1 quad = 4 pts = 12 floats
#define NTHREADS 256
#define NF4      (3 * NQUADS)      // 3,000,000 float4s in the stream
#define NTILES   ((NQUADS + NTHREADS - 1) / NTHREADS)   // 3907 tiles of 256 quads
#define TPB      4                                      // tiles per block
#define NBLOCKS_P ((NTILES + TPB - 1) / TPB)            // 977 (< 6/CU cap: all resident)

// ---------------------------------------------------------------------------
// Round 14 = round 13 (verified 24.7us: dbuf LDS, 1 barrier/tile, store-last)
// with TPB 2->4: half the block prologues/epilogues, fully-resident grid
// (977 blocks ~ 3.8/CU), longer steady-state pipeline. Bounds checks hoisted
// to a uniform branch (only tile 3906 is partial).
// Lessons kept: no device fences (r3), no float atomics (r12), plain stores
// (r6), 48B/thread footprint (r2/r9), coalesced global IO via LDS (r10),
// register prefetch (r11), store-after-barrier (r13).
// ---------------------------------------------------------------------------
__global__ __launch_bounds__(NTHREADS) void proj_kernel(
    const float4* __restrict__ pts,
    const float* __restrict__ xp, const float* __restrict__ yp,
    const float* __restrict__ zp, const float* __restrict__ rollp,
    const float* __restrict__ pitchp, const float* __restrict__ yawp,
    float4* __restrict__ vout, float* __restrict__ partials)
{
    __shared__ float sRT[12];
    __shared__ float4 buf[2][3 * NTHREADS];    // 24 KiB double buffer
    __shared__ float sred[NTHREADS / 64];

    const int t = threadIdx.x;
    const int tbase = blockIdx.x * TPB;

    // --- prologue: issue tile0 loads; thread-0 trig overlaps load latency ---
    {
        float4 p0 = make_float4(0.f, 0.f, 0.f, 0.f), p1 = p0, p2 = p0;
        const size_t fb = (size_t)tbase * (3 * NTHREADS) + t;
        if (tbase < NTILES - 1) {              // full tile: unchecked
            p0 = pts[fb];
            p1 = pts[fb + NTHREADS];
            p2 = pts[fb + 2 * NTHREADS];
        } else {                               // partial tile
            if (fb                < NF4) p0 = pts[fb];
            if (fb +     NTHREADS < NF4) p1 = pts[fb + NTHREADS];
            if (fb + 2 * NTHREADS < NF4) p2 = pts[fb + 2 * NTHREADS];
        }

        if (t == 0) {
            const float r = rollp[0], p = pitchp[0], ya = yawp[0];
            const float cr = cosf(r),  sr = sinf(r);
            const float cp = cosf(p),  sp = sinf(p);
            const float cy = cosf(ya), sy = sinf(ya);
            // R = Rx @ Ry @ Rz, row-major
            sRT[0] = cp * cy;                 sRT[1] = -cp * sy;                sRT[2] = sp;
            sRT[3] = cr * sy + sr * sp * cy;  sRT[4] = cr * cy - sr * sp * sy;  sRT[5] = -sr * cp;
            sRT[6] = sr * sy - cr * sp * cy;  sRT[7] = sr * cy + cr * sp * sy;  sRT[8] = cr * cp;
            sRT[9] = xp[0]; sRT[10] = yp[0]; sRT[11] = zp[0];
        }
        buf[0][t]                = p0;
        buf[0][t + NTHREADS]     = p1;
        buf[0][t + 2 * NTHREADS] = p2;
    }
    __syncthreads();                                    // tile0 + sRT visible

    const float R00 = sRT[0], R01 = sRT[1], R02 = sRT[2];
    const float R10 = sRT[3], R11 = sRT[4], R12 = sRT[5];
    const float R20 = sRT[6], R21 = sRT[7], R22 = sRT[8];
    const float Tx  = sRT[9], Ty  = sRT[10], Tz = sRT[11];

    float acc = 0.0f;

#pragma unroll
    for (int i = 0; i < TPB; ++i) {
        const int tid = tbase + i;
        const int cur = i & 1;
        if (tid >= NTILES) break;

        // Read own quad (3x ds_read_b128 from own 48B region of buf[cur]).
        const float4* __restrict__ mt =
            (const float4*)((const float*)&buf[cur][0] + 12 * t);
        const float4 a = mt[0];
        const float4 b = mt[1];
        const float4 c = mt[2];

        // Issue next tile's global loads; latency hides under compute.
        float4 n0 = make_float4(0.f, 0.f, 0.f, 0.f), n1 = n0, n2 = n0;
        if (i + 1 < TPB && tid + 1 < NTILES) {
            const size_t fb = (size_t)(tid + 1) * (3 * NTHREADS) + t;
            if (tid + 1 < NTILES - 1) {        // full tile: unchecked
                n0 = pts[fb];
                n1 = pts[fb + NTHREADS];
                n2 = pts[fb + 2 * NTHREADS];
            } else {
                if (fb                < NF4) n0 = pts[fb];
                if (fb +     NTHREADS < NF4) n1 = pts[fb + NTHREADS];
                if (fb + 2 * NTHREADS < NF4) n2 = pts[fb + 2 * NTHREADS];
            }
        }

        const int q = tid * NTHREADS + t;               // global quad index
        float4 o0 = make_float4(0.f, 0.f, 0.f, 0.f), o1 = o0, o2 = o0;
        if (q < NQUADS) {
            const float px[4] = {a.x, a.w, b.z, c.y};
            const float py[4] = {a.y, b.x, b.w, c.z};
            const float pz[4] = {a.z, b.y, c.x, c.w};
            float vx[4], vy[4], vz[4];

#pragma unroll
            for (int k = 0; k < 4; ++k) {
                const float q0f = px[k] - Tx;
                const float q1f = py[k] - Ty;
                const float q2f = pz[k] - Tz;
                // v = q @ R   (v_j = sum_i q_i * R[i][j])
                const float v0 = q0f * R00 + q1f * R10 + q2f * R20;
                const float v1 = q0f * R01 + q1f * R11 + q2f * R21;
                const float v2 = q0f * R02 + q1f * R12 + q2f * R22;

                const bool dist = (v2 > 1.0f) && (v2 < 10.0f);

                // ph = v @ K^T ; ph[2] == v2
                const float ph0 = v0 * 600.0f + v2 * 640.0f;
                const float ph1 = v1 * 600.0f + v2 * 360.0f;
                const float u = ph0 / v2;        // IEEE div: mask bit-exactness
                const float w = ph1 / v2;
                const bool fov = (v2 > 0.0f) && (u > 1.0f) && (u < 1279.0f) &&
                                 (w > 1.0f) && (w < 719.0f);
                const bool m = dist && fov;

                const float d  = sqrtf(v0 * v0 + v1 * v1 + v2 * v2);
                const float t2 = (d - 4.0f) * 0.5f;     // (d - MU) / SIGMA
                acc += m ? __expf(-0.5f * t2 * t2) : 0.0f;

                vx[k] = m ? v0 : 0.0f;
                vy[k] = m ? v1 : 0.0f;
                vz[k] = m ? v2 : 0.0f;
            }
            o0 = make_float4(vx[0], vy[0], vz[0], vx[1]);
            o1 = make_float4(vy[1], vz[1], vx[2], vy[2]);
            o2 = make_float4(vz[2], vx[3], vy[3], vz[3]);
        }

        // Writeback to own region of buf[cur].
        float4* __restrict__ mtw = (float4*)((float*)&buf[cur][0] + 12 * t);
        mtw[0] = o0; mtw[1] = o1; mtw[2] = o2;

        // Stage next tile into the OTHER buffer (waits on prefetch loads).
        // Same-thread same-slot vs the pending store of iter i-1: in-thread
        // DS ordering suffices; cross-thread pairs are barrier-separated.
        if (i + 1 < TPB && tid + 1 < NTILES) {
            buf[cur ^ 1][t]                = n0;
            buf[cur ^ 1][t + NTHREADS]     = n1;
            buf[cur ^ 1][t + 2 * NTHREADS] = n2;
        }

        __syncthreads();    // the ONE barrier: writeback + stage visible

        // Coalesced store - LAST op; its drain hides under next tile compute.
        {
            const size_t fb = (size_t)tid * (3 * NTHREADS) + t;
            if (tid < NTILES - 1) {            // full tile: unchecked
                vout[fb]                = buf[cur][t];
                vout[fb + NTHREADS]     = buf[cur][t + NTHREADS];
                vout[fb + 2 * NTHREADS] = buf[cur][t + 2 * NTHREADS];
            } else {
                if (fb                < NF4) vout[fb]                = buf[cur][t];
                if (fb +     NTHREADS < NF4) vout[fb + NTHREADS]     = buf[cur][t + NTHREADS];
                if (fb + 2 * NTHREADS < NF4) vout[fb + 2 * NTHREADS] = buf[cur][t + 2 * NTHREADS];
            }
        }
    }

    // Per-block deterministic reduction (acc=0 for invalid threads).
#pragma unroll
    for (int off = 32; off > 0; off >>= 1)
        acc += __shfl_down(acc, off, 64);
    if ((t & 63) == 0) sred[t >> 6] = acc;
    __syncthreads();
    if (t == 0) {
        float tot = 0.0f;
#pragma unroll
        for (int i = 0; i < NTHREADS / 64; ++i) tot += sred[i];
        partials[blockIdx.x] = tot;
    }
}

// ---------------------------------------------------------------------------
// Loss kernel: sum partials in fixed order -> loss (cross-block sync point;
// no fences, no float atomics).
// ---------------------------------------------------------------------------
__global__ __launch_bounds__(256) void loss_kernel(const float* __restrict__ partials,
                                                   int n, float* __restrict__ loss_out) {
    __shared__ float sdata[4];
    float acc = 0.0f;
    for (int i = threadIdx.x; i < n; i += 256) acc += partials[i];
#pragma unroll
    for (int off = 32; off > 0; off >>= 1)
        acc += __shfl_down(acc, off, 64);
    if ((threadIdx.x & 63) == 0) sdata[threadIdx.x >> 6] = acc;
    __syncthreads();
    if (threadIdx.x == 0) {
        const float tot = sdata[0] + sdata[1] + sdata[2] + sdata[3];
        loss_out[0] = 1.0f / (tot + 1e-6f);
    }
}

extern "C" void kernel_launch(void* const* d_in, const int* in_sizes, int n_in,
                              void* d_out, int out_size, void* d_ws, size_t ws_size,
                              hipStream_t stream) {
    const float4* pts  = (const float4*)d_in[0];
    const float* x     = (const float*)d_in[1];
    const float* y     = (const float*)d_in[2];
    const float* z     = (const float*)d_in[3];
    const float* roll  = (const float*)d_in[4];
    const float* pitch = (const float*)d_in[5];
    const float* yaw   = (const float*)d_in[6];

    float* out   = (float*)d_out;   // [0..12M) verts, [12M] loss
    float* parts = (float*)d_ws;    // NBLOCKS_P floats

    proj_kernel<<<NBLOCKS_P, NTHREADS, 0, stream>>>(pts, x, y, z, roll, pitch, yaw,
                                                    (float4*)out, parts);
    loss_kernel<<<1, 256, 0, stream>>>(parts, NBLOCKS_P, out + (size_t)3 * N_PTS);
}